// Round 1
// baseline (98.701 us; speedup 1.0000x reference)
//
#include <hip/hip_runtime.h>
#include <math.h>

#define KK 5
#define PADK 2
#define C_IN 8
#define O_OUT 8
#define HH 512
#define WW 512
#define TH 16
#define TW 64
#define LROWS (TH + 2 * PADK)   // 20
#define LCOLS (TW + 2 * PADK)   // 68

__global__ __launch_bounds__(256, 3)
void dilation2d_kernel(const float* __restrict__ x,
                       const float* __restrict__ wgt,
                       float* __restrict__ out) {
    __shared__ float lds[C_IN][LROWS][LCOLS];   // 8*20*68*4 = 43,520 B

    const int tid = threadIdx.x;
    const int w0 = blockIdx.x * TW;
    const int h0 = blockIdx.y * TH;
    const int n  = blockIdx.z;

    // ---- stage x tile into LDS with zero halo (reproduces zero padding) ----
    const float* xn = x + (size_t)n * C_IN * HH * WW;
    float* ldsf = &lds[0][0][0];
    for (int idx = tid; idx < C_IN * LROWS * LCOLS; idx += 256) {
        int c   = idx / (LROWS * LCOLS);
        int rem = idx - c * (LROWS * LCOLS);
        int r   = rem / LCOLS;
        int col = rem - r * LCOLS;
        int gh = h0 - PADK + r;
        int gw = w0 - PADK + col;
        float v = 0.0f;
        if ((unsigned)gh < (unsigned)HH && (unsigned)gw < (unsigned)WW)
            v = xn[(c * HH + gh) * WW + gw];
        ldsf[idx] = v;
    }
    __syncthreads();

    // thread -> 4 consecutive-w pixels in one row
    const int tx = tid & 15;        // 16 groups of 4 pixels across 64 cols
    const int ty = tid >> 4;        // 16 rows
    const int colb = tx * 4;        // LDS col base (pixel p, tap dx -> col colb+p+dx)

    float acc[O_OUT][4];
    #pragma unroll
    for (int o = 0; o < O_OUT; ++o) {
        #pragma unroll
        for (int p = 0; p < 4; ++p) acc[o][p] = -INFINITY;
    }

    for (int c = 0; c < C_IN; ++c) {
        #pragma unroll
        for (int dy = 0; dy < KK; ++dy) {
            const float* lrow = &lds[c][ty + dy][colb];
            float4 va = *(const float4*)(lrow);
            float4 vb = *(const float4*)(lrow + 4);
            float v[8];
            v[0] = va.x; v[1] = va.y; v[2] = va.z; v[3] = va.w;
            v[4] = vb.x; v[5] = vb.y; v[6] = vb.z; v[7] = vb.w;
            const float* wp = wgt + (c * KK + dy) * KK;   // + o*C*K*K + dx
            #pragma unroll
            for (int o = 0; o < O_OUT; ++o) {
                const float* wpo = wp + o * (C_IN * KK * KK);
                // compute 5 taps per pixel; chain written to allow v_max3 fusion
                #pragma unroll
                for (int p = 0; p < 4; ++p) {
                    float t0 = v[p + 0] + wpo[0];
                    float t1 = v[p + 1] + wpo[1];
                    float t2 = v[p + 2] + wpo[2];
                    float t3 = v[p + 3] + wpo[3];
                    float t4 = v[p + 4] + wpo[4];
                    float m01 = fmaxf(t0, t1);          // -> max3 with acc
                    float m234 = fmaxf(fmaxf(t2, t3), t4);
                    acc[o][p] = fmaxf(fmaxf(acc[o][p], m01), m234);
                }
            }
        }
    }

    // ---- store: 4 consecutive pixels -> one float4, coalesced ----
    float* onp = out + (size_t)n * O_OUT * HH * WW;
    const int h = h0 + ty;
    #pragma unroll
    for (int o = 0; o < O_OUT; ++o) {
        float4 r;
        r.x = acc[o][0]; r.y = acc[o][1]; r.z = acc[o][2]; r.w = acc[o][3];
        *(float4*)(&onp[((size_t)o * HH + h) * WW + (w0 + colb)]) = r;
    }
}

extern "C" void kernel_launch(void* const* d_in, const int* in_sizes, int n_in,
                              void* d_out, int out_size, void* d_ws, size_t ws_size,
                              hipStream_t stream) {
    const float* x   = (const float*)d_in[0];
    const float* wgt = (const float*)d_in[1];
    float* out = (float*)d_out;

    dim3 grid(WW / TW, HH / TH, 4);   // (8, 32, 4)
    dim3 block(256);
    dilation2d_kernel<<<grid, block, 0, stream>>>(x, wgt, out);
}

// Round 2
// 79.147 us; speedup vs baseline: 1.2471x; 1.2471x over previous
//
#include <hip/hip_runtime.h>
#include <math.h>
#include <stdint.h>

typedef _Float16 half2v __attribute__((ext_vector_type(2)));

#define KK 5
#define PADK 2
#define C_IN 8
#define O_OUT 8
#define HH 512
#define WW 512
#define TH 16
#define TW 64
#define LROWS (TH + 2 * PADK)   // 20
#define LPAIRS 36               // 72 f16 cols (68 used), stride 144 B
#define NW (O_OUT * C_IN * KK * KK)  // 1600 weights

static __device__ __forceinline__ half2v bc_h2(uint32_t u) {
    return __builtin_bit_cast(half2v, u);
}
static __device__ __forceinline__ half2v emax(half2v a, half2v b) {
    return __builtin_elementwise_max(a, b);
}

// ---- prep: fp32 weights -> packed (h,h) f16 pairs in workspace ----
__global__ void prep_weights_kernel(const float* __restrict__ w,
                                    uint32_t* __restrict__ wp) {
    int i = blockIdx.x * 256 + threadIdx.x;
    if (i < NW) {
        _Float16 h = (_Float16)w[i];
        uint16_t hb = __builtin_bit_cast(uint16_t, h);
        wp[i] = ((uint32_t)hb << 16) | (uint32_t)hb;
    }
}

template <bool USE_WS>
__global__ __launch_bounds__(256, 4)
void dil_kernel(const float* __restrict__ x,
                const float* __restrict__ wf,
                const uint32_t* __restrict__ wp,
                float* __restrict__ out) {
    __shared__ uint32_t lds[C_IN][LROWS][LPAIRS];   // 23,040 B

    const int tid = threadIdx.x;
    const int w0 = blockIdx.x * TW;
    const int h0 = blockIdx.y * TH;
    const int n  = blockIdx.z;

    // ---- stage x tile into LDS as packed f16 pairs, zero halo ----
    const float* xn = x + (size_t)n * (C_IN * HH * WW);
    for (int idx = tid; idx < C_IN * LROWS * LPAIRS; idx += 256) {
        int c   = idx / (LROWS * LPAIRS);
        int rem = idx - c * (LROWS * LPAIRS);
        int r   = rem / LPAIRS;
        int jp  = rem - r * LPAIRS;
        int gh = h0 - PADK + r;
        int gw = w0 - PADK + 2 * jp;
        float v0 = 0.f, v1 = 0.f;
        if ((unsigned)gh < (unsigned)HH) {
            const float* row = xn + ((size_t)c * HH + gh) * WW;
            if ((unsigned)gw < (unsigned)WW) v0 = row[gw];
            if ((unsigned)(gw + 1) < (unsigned)WW) v1 = row[gw + 1];
        }
        _Float16 a = (_Float16)v0, b = (_Float16)v1;
        uint32_t u = ((uint32_t)__builtin_bit_cast(uint16_t, b) << 16) |
                     (uint32_t)__builtin_bit_cast(uint16_t, a);
        (&lds[0][0][0])[idx] = u;
    }
    __syncthreads();

    // thread -> 4 consecutive-w pixels (2 f16 pairs) in one row, all 8 o
    const int tx = tid & 15;
    const int ty = tid >> 4;
    const int pb = 2 * tx;          // pair-index base; pixels 4*tx .. 4*tx+3

    const uint32_t NINF = 0xFC00FC00u;  // (-inf, -inf) f16
    half2v acc[O_OUT][2];
    #pragma unroll
    for (int o = 0; o < O_OUT; ++o) {
        acc[o][0] = bc_h2(NINF);
        acc[o][1] = bc_h2(NINF);
    }

    for (int c = 0; c < C_IN; ++c) {
        #pragma unroll
        for (int dy = 0; dy < KK; ++dy) {
            const uint32_t* lrow = &lds[c][ty + dy][pb];
            uint2 A = *(const uint2*)lrow;          // pairs 0,1 (px 0..3)
            uint2 B = *(const uint2*)(lrow + 2);    // pairs 2,3 (px 4..7)
            uint32_t u0 = A.x, u1 = A.y, u2 = B.x, u3 = B.y;
            uint32_t s0 = (u0 >> 16) | (u1 << 16);  // v_alignbit
            uint32_t s1 = (u1 >> 16) | (u2 << 16);
            uint32_t s2 = (u2 >> 16) | (u3 << 16);
            half2v H0 = bc_h2(u0), H1 = bc_h2(u1), H2 = bc_h2(u2), H3 = bc_h2(u3);
            half2v S0 = bc_h2(s0), S1 = bc_h2(s1), S2 = bc_h2(s2);

            const int wbase = (c * KK + dy) * KK;
            #pragma unroll
            for (int o = 0; o < O_OUT; ++o) {
                half2v W0, W1, W2, W3, W4;
                const int off = o * (C_IN * KK * KK) + wbase;
                if (USE_WS) {
                    W0 = bc_h2(wp[off + 0]);
                    W1 = bc_h2(wp[off + 1]);
                    W2 = bc_h2(wp[off + 2]);
                    W3 = bc_h2(wp[off + 3]);
                    W4 = bc_h2(wp[off + 4]);
                } else {
                    _Float16 h0w = (_Float16)wf[off + 0];
                    _Float16 h1w = (_Float16)wf[off + 1];
                    _Float16 h2w = (_Float16)wf[off + 2];
                    _Float16 h3w = (_Float16)wf[off + 3];
                    _Float16 h4w = (_Float16)wf[off + 4];
                    W0 = (half2v){h0w, h0w}; W1 = (half2v){h1w, h1w};
                    W2 = (half2v){h2w, h2w}; W3 = (half2v){h3w, h3w};
                    W4 = (half2v){h4w, h4w};
                }
                // pair 0: pixels (0,1)
                {
                    half2v t0 = H0 + W0, t1 = S0 + W1, t2 = H1 + W2,
                           t3 = S1 + W3, t4 = H2 + W4;
                    half2v m01 = emax(t0, t1), m23 = emax(t2, t3);
                    acc[o][0] = emax(acc[o][0], emax(emax(m01, m23), t4));
                }
                // pair 1: pixels (2,3)
                {
                    half2v t0 = H1 + W0, t1 = S1 + W1, t2 = H2 + W2,
                           t3 = S2 + W3, t4 = H3 + W4;
                    half2v m01 = emax(t0, t1), m23 = emax(t2, t3);
                    acc[o][1] = emax(acc[o][1], emax(emax(m01, m23), t4));
                }
            }
        }
    }

    // ---- store: 4 consecutive pixels -> one float4, coalesced ----
    float* onp = out + (size_t)n * (O_OUT * HH * WW);
    const int h = h0 + ty;
    const int wcol = w0 + 4 * tx;
    #pragma unroll
    for (int o = 0; o < O_OUT; ++o) {
        float4 r;
        r.x = (float)acc[o][0].x;
        r.y = (float)acc[o][0].y;
        r.z = (float)acc[o][1].x;
        r.w = (float)acc[o][1].y;
        *(float4*)(&onp[((size_t)o * HH + h) * WW + wcol]) = r;
    }
}

extern "C" void kernel_launch(void* const* d_in, const int* in_sizes, int n_in,
                              void* d_out, int out_size, void* d_ws, size_t ws_size,
                              hipStream_t stream) {
    const float* x   = (const float*)d_in[0];
    const float* wgt = (const float*)d_in[1];
    float* out = (float*)d_out;

    dim3 grid(WW / TW, HH / TH, 4);   // (8, 32, 4) = 1024 blocks
    dim3 block(256);

    if (ws_size >= (size_t)NW * 4) {
        uint32_t* wp = (uint32_t*)d_ws;
        prep_weights_kernel<<<(NW + 255) / 256, 256, 0, stream>>>(wgt, wp);
        dil_kernel<true><<<grid, block, 0, stream>>>(x, wgt, wp, out);
    } else {
        dil_kernel<false><<<grid, block, 0, stream>>>(x, wgt, nullptr, out);
    }
}

// Round 4
// 74.978 us; speedup vs baseline: 1.3164x; 1.0556x over previous
//
#include <hip/hip_runtime.h>
#include <math.h>
#include <stdint.h>

typedef _Float16 half2v __attribute__((ext_vector_type(2)));

#define KK 5
#define PADK 2
#define C_IN 8
#define O_OUT 8
#define HH 512
#define WW 512
#define TH 8
#define TW 64
#define LROWS (TH + 2 * PADK)   // 12
#define LPAIRS 36               // 72 f16 cols (68 used)
#define NW (O_OUT * C_IN * KK * KK)  // 1600

static __device__ __forceinline__ half2v bc_h2(uint32_t u) {
    return __builtin_bit_cast(half2v, u);
}
static __device__ __forceinline__ half2v emax(half2v a, half2v b) {
    return __builtin_elementwise_max(a, b);
}

// ---- prep: fp32 weights -> packed (h,h) f16, reordered to [c][dy][o][dx] ----
// Consumption order per (c,dy) is a contiguous 40-dword run -> wide s_loads.
__global__ void prep_weights_kernel(const float* __restrict__ w,
                                    uint32_t* __restrict__ wp) {
    int i = blockIdx.x * 256 + threadIdx.x;   // i over (o,c,dy,dx)
    if (i < NW) {
        int dx = i % KK;
        int t  = i / KK;
        int dy = t % KK;  t /= KK;
        int c  = t % C_IN;
        int o  = t / C_IN;
        _Float16 h = (_Float16)w[i];
        uint16_t hb = __builtin_bit_cast(uint16_t, h);
        int j = ((c * KK + dy) * O_OUT + o) * KK + dx;
        wp[j] = ((uint32_t)hb << 16) | (uint32_t)hb;
    }
}

template <bool USE_WS>
__global__ __launch_bounds__(256, 8)
void dil_kernel(const float* __restrict__ x,
                const float* __restrict__ wf,
                const uint32_t* __restrict__ wp,
                float* __restrict__ out) {
    __shared__ uint32_t lds[C_IN][LROWS][LPAIRS];   // 13,824 B

    const int tid = threadIdx.x;
    const int w0 = blockIdx.x * TW;
    const int h0 = blockIdx.y * TH;
    const int n  = blockIdx.z;

    // ---- stage x tile into LDS as packed f16 pairs, zero halo ----
    const float* xn = x + (size_t)n * (C_IN * HH * WW);
    for (int idx = tid; idx < C_IN * LROWS * LPAIRS; idx += 256) {
        int c   = idx / (LROWS * LPAIRS);
        int rem = idx - c * (LROWS * LPAIRS);
        int r   = rem / LPAIRS;
        int jp  = rem - r * LPAIRS;
        int gh = h0 - PADK + r;
        int gw = w0 - PADK + 2 * jp;
        float v0 = 0.f, v1 = 0.f;
        if ((unsigned)gh < (unsigned)HH) {
            const float* row = xn + ((size_t)c * HH + gh) * WW;
            if ((unsigned)gw < (unsigned)WW) v0 = row[gw];
            if ((unsigned)(gw + 1) < (unsigned)WW) v1 = row[gw + 1];
        }
        _Float16 a = (_Float16)v0, b = (_Float16)v1;
        uint32_t u = ((uint32_t)__builtin_bit_cast(uint16_t, b) << 16) |
                     (uint32_t)__builtin_bit_cast(uint16_t, a);
        (&lds[0][0][0])[idx] = u;
    }
    __syncthreads();

    // thread -> 2 consecutive-w pixels (one f16 pair) in one row, all 8 o
    const int tx = tid & 31;        // 32 pairs across 64 cols
    const int ty = tid >> 5;        // 8 rows

    const uint32_t NINF = 0xFC00FC00u;  // (-inf, -inf) f16
    half2v acc[O_OUT];
    #pragma unroll
    for (int o = 0; o < O_OUT; ++o) acc[o] = bc_h2(NINF);

    for (int c = 0; c < C_IN; ++c) {
        #pragma unroll
        for (int dy = 0; dy < KK; ++dy) {
            const uint32_t* lrow = &lds[c][ty + dy][tx];
            uint32_t u0 = lrow[0];
            uint32_t u1 = lrow[1];
            uint32_t u2 = lrow[2];
            uint32_t s0 = (u0 >> 16) | (u1 << 16);  // v_alignbit
            uint32_t s1 = (u1 >> 16) | (u2 << 16);
            half2v H0 = bc_h2(u0), H1 = bc_h2(u1), H2 = bc_h2(u2);
            half2v S0 = bc_h2(s0), S1 = bc_h2(s1);

            const int wbase = (c * KK + dy) * (O_OUT * KK);   // contiguous 40 dwords
            #pragma unroll
            for (int o = 0; o < O_OUT; ++o) {
                half2v W0, W1, W2, W3, W4;
                if (USE_WS) {
                    const int off = wbase + o * KK;
                    W0 = bc_h2(wp[off + 0]);
                    W1 = bc_h2(wp[off + 1]);
                    W2 = bc_h2(wp[off + 2]);
                    W3 = bc_h2(wp[off + 3]);
                    W4 = bc_h2(wp[off + 4]);
                } else {
                    const int off = ((o * C_IN + c) * KK + dy) * KK;
                    _Float16 h0w = (_Float16)wf[off + 0];
                    _Float16 h1w = (_Float16)wf[off + 1];
                    _Float16 h2w = (_Float16)wf[off + 2];
                    _Float16 h3w = (_Float16)wf[off + 3];
                    _Float16 h4w = (_Float16)wf[off + 4];
                    W0 = (half2v){h0w, h0w}; W1 = (half2v){h1w, h1w};
                    W2 = (half2v){h2w, h2w}; W3 = (half2v){h3w, h3w};
                    W4 = (half2v){h4w, h4w};
                }
                half2v t0 = H0 + W0, t1 = S0 + W1, t2 = H1 + W2,
                       t3 = S1 + W3, t4 = H2 + W4;
                half2v m01 = emax(t0, t1), m23 = emax(t2, t3);
                acc[o] = emax(acc[o], emax(emax(m01, m23), t4));
            }
        }
    }

    // ---- store: 2 consecutive pixels -> one float2, coalesced ----
    float* onp = out + (size_t)n * (O_OUT * HH * WW);
    const int h = h0 + ty;
    const int wcol = w0 + 2 * tx;
    #pragma unroll
    for (int o = 0; o < O_OUT; ++o) {
        float2 r;
        r.x = (float)acc[o].x;
        r.y = (float)acc[o].y;
        *(float2*)(&onp[((size_t)o * HH + h) * WW + wcol]) = r;
    }
}

extern "C" void kernel_launch(void* const* d_in, const int* in_sizes, int n_in,
                              void* d_out, int out_size, void* d_ws, size_t ws_size,
                              hipStream_t stream) {
    const float* x   = (const float*)d_in[0];
    const float* wgt = (const float*)d_in[1];
    float* out = (float*)d_out;

    dim3 grid(WW / TW, HH / TH, 4);   // (8, 64, 4) = 2048 blocks
    dim3 block(256);

    if (ws_size >= (size_t)NW * 4) {
        uint32_t* wp = (uint32_t*)d_ws;
        prep_weights_kernel<<<(NW + 255) / 256, 256, 0, stream>>>(wgt, wp);
        dil_kernel<true><<<grid, block, 0, stream>>>(x, wgt, wp, out);
    } else {
        dil_kernel<false><<<grid, block, 0, stream>>>(x, wgt, nullptr, out);
    }
}

// Round 5
// 74.826 us; speedup vs baseline: 1.3191x; 1.0020x over previous
//
#include <hip/hip_runtime.h>
#include <math.h>
#include <stdint.h>

typedef _Float16 half2v __attribute__((ext_vector_type(2)));

#define KK 5
#define PADK 2
#define C_IN 8
#define O_OUT 8
#define HH 512
#define WW 512
#define TH 8
#define TW 128
#define LROWS (TH + 2 * PADK)   // 12
#define LPAIRS 68               // dwords per row = 136 f16 cols (132 used)
#define NW (O_OUT * C_IN * KK * KK)  // 1600

static __device__ __forceinline__ half2v bc_h2(uint32_t u) {
    return __builtin_bit_cast(half2v, u);
}
static __device__ __forceinline__ half2v emax(half2v a, half2v b) {
    return __builtin_elementwise_max(a, b);
}

// ---- prep: fp32 weights -> packed (h,h) f16, reordered to [c][dy][o][dx] ----
__global__ void prep_weights_kernel(const float* __restrict__ w,
                                    uint32_t* __restrict__ wp) {
    int i = blockIdx.x * 256 + threadIdx.x;   // i over (o,c,dy,dx)
    if (i < NW) {
        int dx = i % KK;
        int t  = i / KK;
        int dy = t % KK;  t /= KK;
        int c  = t % C_IN;
        int o  = t / C_IN;
        _Float16 h = (_Float16)w[i];
        uint16_t hb = __builtin_bit_cast(uint16_t, h);
        int j = ((c * KK + dy) * O_OUT + o) * KK + dx;
        wp[j] = ((uint32_t)hb << 16) | (uint32_t)hb;
    }
}

template <bool USE_WS>
__global__ __launch_bounds__(512, 8)
void dil_kernel(const float* __restrict__ x,
                const float* __restrict__ wf,
                const uint32_t* __restrict__ wp,
                float* __restrict__ out) {
    __shared__ uint32_t lds[C_IN][LROWS][LPAIRS];   // 26,112 B

    const int tid = threadIdx.x;
    const int w0 = blockIdx.x * TW;
    const int h0 = blockIdx.y * TH;
    const int n  = blockIdx.z;

    // ---- stage x tile into LDS as packed f16 pairs, zero halo ----
    const float* xn = x + (size_t)n * (C_IN * HH * WW);
    for (int idx = tid; idx < C_IN * LROWS * LPAIRS; idx += 512) {
        int c   = idx / (LROWS * LPAIRS);
        int rem = idx - c * (LROWS * LPAIRS);
        int r   = rem / LPAIRS;
        int jp  = rem - r * LPAIRS;
        int gh = h0 - PADK + r;
        int gw = w0 - PADK + 2 * jp;
        float v0 = 0.f, v1 = 0.f;
        if ((unsigned)gh < (unsigned)HH) {
            const float* row = xn + ((size_t)c * HH + gh) * WW;
            if ((unsigned)gw < (unsigned)WW) v0 = row[gw];
            if ((unsigned)(gw + 1) < (unsigned)WW) v1 = row[gw + 1];
        }
        _Float16 a = (_Float16)v0, b = (_Float16)v1;
        uint32_t u = ((uint32_t)__builtin_bit_cast(uint16_t, b) << 16) |
                     (uint32_t)__builtin_bit_cast(uint16_t, a);
        (&lds[0][0][0])[idx] = u;
    }
    __syncthreads();

    // wave = one output row; lane = one f16 pair (2 pixels), all 8 o
    const int tx  = tid & 63;                                   // pair index
    const int wid = __builtin_amdgcn_readfirstlane(tid >> 6);   // row & c-stagger

    const uint32_t NINF = 0xFC00FC00u;  // (-inf, -inf) f16
    half2v acc[O_OUT];
    #pragma unroll
    for (int o = 0; o < O_OUT; ++o) acc[o] = bc_h2(NINF);

    for (int ci = 0; ci < C_IN; ++ci) {
        const int c = (ci + wid) & 7;   // per-wave channel rotation (max commutes)

        // batch ALL pixel ds_reads for this c up front -> one lgkm drain
        uint32_t u[KK][3];
        #pragma unroll
        for (int dy = 0; dy < KK; ++dy) {
            const uint32_t* lrow = &lds[c][wid + dy][tx];
            u[dy][0] = lrow[0];
            u[dy][1] = lrow[1];
            u[dy][2] = lrow[2];
        }

        const uint32_t* wc = wp + c * (KK * O_OUT * KK);
        #pragma unroll
        for (int dy = 0; dy < KK; ++dy) {
            uint32_t u0 = u[dy][0], u1 = u[dy][1], u2 = u[dy][2];
            uint32_t s0 = (u0 >> 16) | (u1 << 16);  // v_alignbit
            uint32_t s1 = (u1 >> 16) | (u2 << 16);
            half2v H0 = bc_h2(u0), H1 = bc_h2(u1), H2 = bc_h2(u2);
            half2v S0 = bc_h2(s0), S1 = bc_h2(s1);

            #pragma unroll
            for (int o = 0; o < O_OUT; ++o) {
                half2v W0, W1, W2, W3, W4;
                if (USE_WS) {
                    const uint32_t* wd = wc + dy * (O_OUT * KK) + o * KK;
                    W0 = bc_h2(wd[0]);
                    W1 = bc_h2(wd[1]);
                    W2 = bc_h2(wd[2]);
                    W3 = bc_h2(wd[3]);
                    W4 = bc_h2(wd[4]);
                } else {
                    const int off = ((o * C_IN + c) * KK + dy) * KK;
                    _Float16 h0w = (_Float16)wf[off + 0];
                    _Float16 h1w = (_Float16)wf[off + 1];
                    _Float16 h2w = (_Float16)wf[off + 2];
                    _Float16 h3w = (_Float16)wf[off + 3];
                    _Float16 h4w = (_Float16)wf[off + 4];
                    W0 = (half2v){h0w, h0w}; W1 = (half2v){h1w, h1w};
                    W2 = (half2v){h2w, h2w}; W3 = (half2v){h3w, h3w};
                    W4 = (half2v){h4w, h4w};
                }
                half2v t0 = H0 + W0, t1 = S0 + W1, t2 = H1 + W2,
                       t3 = S1 + W3, t4 = H2 + W4;
                half2v m01 = emax(t0, t1), m23 = emax(t2, t3);
                acc[o] = emax(acc[o], emax(emax(m01, m23), t4));
            }
        }
    }

    // ---- store: 2 consecutive pixels -> one float2, coalesced ----
    float* onp = out + (size_t)n * (O_OUT * HH * WW);
    const int h = h0 + wid;
    const int wcol = w0 + 2 * tx;
    #pragma unroll
    for (int o = 0; o < O_OUT; ++o) {
        float2 r;
        r.x = (float)acc[o].x;
        r.y = (float)acc[o].y;
        *(float2*)(&onp[((size_t)o * HH + h) * WW + wcol]) = r;
    }
}

extern "C" void kernel_launch(void* const* d_in, const int* in_sizes, int n_in,
                              void* d_out, int out_size, void* d_ws, size_t ws_size,
                              hipStream_t stream) {
    const float* x   = (const float*)d_in[0];
    const float* wgt = (const float*)d_in[1];
    float* out = (float*)d_out;

    dim3 grid(WW / TW, HH / TH, 4);   // (4, 64, 4) = 1024 blocks x 512 thr
    dim3 block(512);

    if (ws_size >= (size_t)NW * 4) {
        uint32_t* wp = (uint32_t*)d_ws;
        prep_weights_kernel<<<(NW + 255) / 256, 256, 0, stream>>>(wgt, wp);
        dil_kernel<true><<<grid, block, 0, stream>>>(x, wgt, wp, out);
    } else {
        dil_kernel<false><<<grid, block, 0, stream>>>(x, wgt, nullptr, out);
    }
}

// Round 6
// 74.459 us; speedup vs baseline: 1.3256x; 1.0049x over previous
//
#include <hip/hip_runtime.h>
#include <math.h>
#include <stdint.h>

typedef _Float16 half2v __attribute__((ext_vector_type(2)));

#define KK 5
#define PADK 2
#define C_IN 8
#define O_OUT 8
#define HH 512
#define WW 512
#define TH 8
#define TW 128
#define LROWS (TH + 2 * PADK)   // 12
#define LPAIRS 68               // dwords per row = 136 f16 cols (132 used)
#define NW (O_OUT * C_IN * KK * KK)  // 1600
#define WROW (O_OUT * KK)            // 40 dwords per (c,dy)

static __device__ __forceinline__ half2v bc_h2(uint32_t u) {
    return __builtin_bit_cast(half2v, u);
}
static __device__ __forceinline__ half2v emax(half2v a, half2v b) {
    return __builtin_elementwise_max(a, b);
}

// ---- prep: fp32 weights -> packed (h,h) f16, reordered to [c][dy][o][dx] ----
__global__ void prep_weights_kernel(const float* __restrict__ w,
                                    uint32_t* __restrict__ wp) {
    int i = blockIdx.x * 256 + threadIdx.x;   // i over (o,c,dy,dx)
    if (i < NW) {
        int dx = i % KK;
        int t  = i / KK;
        int dy = t % KK;  t /= KK;
        int c  = t % C_IN;
        int o  = t / C_IN;
        _Float16 h = (_Float16)w[i];
        uint16_t hb = __builtin_bit_cast(uint16_t, h);
        int j = ((c * KK + dy) * O_OUT + o) * KK + dx;
        wp[j] = ((uint32_t)hb << 16) | (uint32_t)hb;
    }
}

template <bool USE_WS>
__global__ __launch_bounds__(512, 8)
void dil_kernel(const float* __restrict__ x,
                const float* __restrict__ wf,
                const uint32_t* __restrict__ wp,
                float* __restrict__ out) {
    __shared__ uint32_t lds[C_IN][LROWS][LPAIRS];   // 26,112 B

    const int tid = threadIdx.x;
    const int w0 = blockIdx.x * TW;
    const int h0 = blockIdx.y * TH;
    const int n  = blockIdx.z;

    // ---- stage x tile into LDS as packed f16 pairs, zero halo ----
    const float* xn = x + (size_t)n * (C_IN * HH * WW);
    for (int idx = tid; idx < C_IN * LROWS * LPAIRS; idx += 512) {
        int c   = idx / (LROWS * LPAIRS);
        int rem = idx - c * (LROWS * LPAIRS);
        int r   = rem / LPAIRS;
        int jp  = rem - r * LPAIRS;
        int gh = h0 - PADK + r;
        int gw = w0 - PADK + 2 * jp;
        float v0 = 0.f, v1 = 0.f;
        if ((unsigned)gh < (unsigned)HH) {
            const float* row = xn + ((size_t)c * HH + gh) * WW;
            if ((unsigned)gw < (unsigned)WW) v0 = row[gw];
            if ((unsigned)(gw + 1) < (unsigned)WW) v1 = row[gw + 1];
        }
        _Float16 a = (_Float16)v0, b = (_Float16)v1;
        uint32_t u = ((uint32_t)__builtin_bit_cast(uint16_t, b) << 16) |
                     (uint32_t)__builtin_bit_cast(uint16_t, a);
        (&lds[0][0][0])[idx] = u;
    }
    __syncthreads();

    // wave = one output row; lane = one f16 pair (2 pixels), all 8 o
    const int tx  = tid & 63;                                   // pair index
    const int wid = __builtin_amdgcn_readfirstlane(tid >> 6);   // row & c-stagger

    const uint32_t NINF = 0xFC00FC00u;  // (-inf, -inf) f16
    half2v acc[O_OUT];
    #pragma unroll
    for (int o = 0; o < O_OUT; ++o) acc[o] = bc_h2(NINF);

    for (int ci = 0; ci < C_IN; ++ci) {
        const int c = (ci + wid) & 7;   // per-wave channel rotation (max commutes)

        // batch ALL pixel ds_reads for this c up front -> one counted drain
        uint32_t u[KK][3];
        #pragma unroll
        for (int dy = 0; dy < KK; ++dy) {
            const uint32_t* lrow = &lds[c][wid + dy][tx];
            u[dy][0] = lrow[0];
            u[dy][1] = lrow[1];
            u[dy][2] = lrow[2];
        }

        const uint32_t* wc = wp + c * (KK * WROW);
        #pragma unroll
        for (int dy = 0; dy < KK; ++dy) {
            // ---- hand-batched weight row: 40 contiguous dwords (160 B) ----
            // -> s_load_dwordx16 x2 + dwordx8, ONE lgkm drain per dy, then
            //    pure VALU. Statically indexed so values live in SGPRs.
            uint32_t wrow[WROW];
            const uint32_t* wd = wc + dy * WROW;
            #pragma unroll
            for (int k = 0; k < WROW; ++k) {
                if (USE_WS) {
                    wrow[k] = wd[k];
                } else {
                    int o  = k / KK;
                    int dx = k - o * KK;
                    const int off = ((o * C_IN + c) * KK + dy) * KK + dx;
                    _Float16 h = (_Float16)wf[off];
                    uint16_t hb = __builtin_bit_cast(uint16_t, h);
                    wrow[k] = ((uint32_t)hb << 16) | (uint32_t)hb;
                }
            }

            uint32_t u0 = u[dy][0], u1 = u[dy][1], u2 = u[dy][2];
            uint32_t s0 = (u0 >> 16) | (u1 << 16);  // v_alignbit
            uint32_t s1 = (u1 >> 16) | (u2 << 16);
            half2v H0 = bc_h2(u0), H1 = bc_h2(u1), H2 = bc_h2(u2);
            half2v S0 = bc_h2(s0), S1 = bc_h2(s1);

            #pragma unroll
            for (int o = 0; o < O_OUT; ++o) {
                half2v W0 = bc_h2(wrow[o * KK + 0]);
                half2v W1 = bc_h2(wrow[o * KK + 1]);
                half2v W2 = bc_h2(wrow[o * KK + 2]);
                half2v W3 = bc_h2(wrow[o * KK + 3]);
                half2v W4 = bc_h2(wrow[o * KK + 4]);
                half2v t0 = H0 + W0, t1 = S0 + W1, t2 = H1 + W2,
                       t3 = S1 + W3, t4 = H2 + W4;
                half2v m01 = emax(t0, t1), m23 = emax(t2, t3);
                acc[o] = emax(acc[o], emax(emax(m01, m23), t4));
            }
        }
    }

    // ---- store: 2 consecutive pixels -> one float2, coalesced ----
    float* onp = out + (size_t)n * (O_OUT * HH * WW);
    const int h = h0 + wid;
    const int wcol = w0 + 2 * tx;
    #pragma unroll
    for (int o = 0; o < O_OUT; ++o) {
        float2 r;
        r.x = (float)acc[o].x;
        r.y = (float)acc[o].y;
        *(float2*)(&onp[((size_t)o * HH + h) * WW + wcol]) = r;
    }
}

extern "C" void kernel_launch(void* const* d_in, const int* in_sizes, int n_in,
                              void* d_out, int out_size, void* d_ws, size_t ws_size,
                              hipStream_t stream) {
    const float* x   = (const float*)d_in[0];
    const float* wgt = (const float*)d_in[1];
    float* out = (float*)d_out;

    dim3 grid(WW / TW, HH / TH, 4);   // (4, 64, 4) = 1024 blocks x 512 thr
    dim3 block(512);

    if (ws_size >= (size_t)NW * 4) {
        uint32_t* wp = (uint32_t*)d_ws;
        prep_weights_kernel<<<(NW + 255) / 256, 256, 0, stream>>>(wgt, wp);
        dil_kernel<true><<<grid, block, 0, stream>>>(x, wgt, wp, out);
    } else {
        dil_kernel<false><<<grid, block, 0, stream>>>(x, wgt, nullptr, out);
    }
}